// Round 13
// baseline (333.276 us; speedup 1.0000x reference)
//
#include <hip/hip_runtime.h>
#include <cstdint>

#define NN 100000
#define EE 1600000
#define HH 128
#define NREP 64
#define PSZ (NN / 8)                 // 12500 rows per partition
#define HPP (PSZ / 2)                // 6250 row-pairs per partition
#define SS 64                        // sub-slices per partition
#define CAP 300000                   // per-partition bucket capacity (entries)
#define NBB 500                      // bucket blocks
#define BCH 3200                     // edges per bucket block (500*3200 = EE)
#define SCAN_CHUNK 512
#define NSCAN ((NN + SCAN_CHUNK - 1) / SCAN_CHUNK)   // 196
#define TPB 4                        // mfma tiles (64 rows) per block

typedef unsigned long long u64;
typedef unsigned short ushort;
typedef unsigned char uchar;
typedef __attribute__((ext_vector_type(8))) short bf16x8;
typedef __attribute__((ext_vector_type(4))) float f32x4;
typedef __attribute__((ext_vector_type(2))) float f32x2;

// ---------- async global->LDS 16B copy (gfx950) ----------
__device__ __forceinline__ void gl2lds16(const void* g, void* l) {
#if __has_builtin(__builtin_amdgcn_global_load_lds)
    __builtin_amdgcn_global_load_lds(
        (const __attribute__((address_space(1))) unsigned int*)g,
        (__attribute__((address_space(3))) unsigned int*)l, 16, 0, 0);
#else
    *(uint4*)l = *(const uint4*)g;
#endif
}

// ---------- bf16 helpers (RNE, finite values) ----------
__device__ __forceinline__ ushort f2bf(float x) {
    union { float f; unsigned u; } v; v.f = x;
    unsigned r = v.u + 0x7fffu + ((v.u >> 16) & 1u);
    return (ushort)(r >> 16);
}
__device__ __forceinline__ float bf2f(unsigned h16) {
    union { unsigned u; float f; } v; v.u = h16 << 16; return v.f;
}

// ---------- fp8 e4m3 helpers (HW cvt) ----------
__device__ __forceinline__ uchar f2fp8(float a) {
    return (uchar)(__builtin_amdgcn_cvt_pk_fp8_f32(a, a, 0, false) & 0xff);
}
__device__ __forceinline__ void unpack8_fp8(uint2 q, float* v) {
    f32x2 a = __builtin_amdgcn_cvt_pk_f32_fp8(q.x, false);
    f32x2 b = __builtin_amdgcn_cvt_pk_f32_fp8(q.x, true);
    f32x2 c = __builtin_amdgcn_cvt_pk_f32_fp8(q.y, false);
    f32x2 d = __builtin_amdgcn_cvt_pk_f32_fp8(q.y, true);
    v[0] = a[0]; v[1] = a[1]; v[2] = b[0]; v[3] = b[1];
    v[4] = c[0]; v[5] = c[1]; v[6] = d[0]; v[7] = d[1];
}

// ---------- monotone float<->uint encoding for atomicMax on floats ----------
__device__ __forceinline__ unsigned encf(float f) {
    int b = __float_as_int(f);
    return (b >= 0) ? ((unsigned)b | 0x80000000u) : ~(unsigned)b;
}
__device__ __forceinline__ float decf(unsigned u) {
    return (u & 0x80000000u) ? __int_as_float((int)(u & 0x7fffffffu))
                             : __int_as_float((int)(~u));
}
#define ENC_NEG_INF 0x007FFFFFu  // encf(-inf)

// ---------- setup: init accumulators + pre-transpose weights to bf16 ----------
// wt is stored PRE-SWIZZLED: chunk g of row n lands at slot g^(n&15).
__global__ void k_setup(float* __restrict__ meansum, unsigned* __restrict__ maxenc,
                        unsigned* __restrict__ lmaxenc, float* __restrict__ esum,
                        int* __restrict__ gtail,
                        const float* __restrict__ w0, const float* __restrict__ w1,
                        const float* __restrict__ w2, ushort* __restrict__ wt) {
    int idx = blockIdx.x * blockDim.x + threadIdx.x;
    if (idx < NREP * HH) { meansum[idx] = 0.f; maxenc[idx] = ENC_NEG_INF; }
    if (idx < 8) gtail[idx] = 0;
    if (idx == 0) { lmaxenc[0] = ENC_NEG_INF; esum[0] = 0.f; }
    if (idx < 3 * HH * HH) {
        int mat = idx >> 14;
        int e = idx & 16383;
        int n = e >> 7, k = e & 127;
        int g = k >> 3, el = k & 7;
        const float* src = (mat == 0) ? w0 : (mat == 1) ? w1 : w2;
        int pos = (mat << 14) | (n << 7) | (((g ^ (n & 15)) << 3) | el);
        wt[pos] = f2bf(src[k * HH + n]);
    }
}

// ---------- bucket: split edges into 8 partition-major packed streams ----------
// entry: (rlocal << 32) | (col << 15) | q15
// NOTE: plain LDS atomics. Ballot-aggregation variant (r5) REGRESSED +14us.
__global__ __launch_bounds__(256) void k_bucket(const int* __restrict__ rows,
                                                const int* __restrict__ cols,
                                                const float* __restrict__ ea,
                                                int* __restrict__ gtail,
                                                u64* __restrict__ ebuck) {
    __shared__ u64 buf[8][1024];   // 64 KB
    __shared__ int cnt8[8];
    __shared__ int rsv[8];
    int t = threadIdx.x;
    if (t < 8) cnt8[t] = 0;
    __syncthreads();
    int e0 = blockIdx.x * BCH;
    int e1 = e0 + BCH;
    for (int ebase = e0; ebase < e1; ebase += 1024) {
        int e = ebase + t * 4;
        if (e < e1) {
            int4 r4 = *(const int4*)(rows + e);
            int4 c4 = *(const int4*)(cols + e);
            float4 a4 = *(const float4*)(ea + e);
            int rr[4] = {r4.x, r4.y, r4.z, r4.w};
            int cc[4] = {c4.x, c4.y, c4.z, c4.w};
            float aa[4] = {a4.x, a4.y, a4.z, a4.w};
#pragma unroll
            for (int j = 0; j < 4; ++j) {
                int p = rr[j] / PSZ;
                int rl = rr[j] - p * PSZ;
                unsigned q = (unsigned)(aa[j] * 32767.0f + 0.5f);
                u64 en = ((u64)rl << 32) | (u64)(((unsigned)cc[j] << 15) | q);
                int idx = atomicAdd(&cnt8[p], 1);
                buf[p][idx] = en;
            }
        }
        __syncthreads();
        if (t < 8) rsv[t] = atomicAdd(&gtail[t], cnt8[t]);
        __syncthreads();
#pragma unroll
        for (int p = 0; p < 8; ++p) {
            int nn = cnt8[p], oo = rsv[p];
            u64* dst = ebuck + (size_t)p * CAP + oo;
            for (int j = t; j < nn; j += 256) dst[j] = buf[p][j];
        }
        __syncthreads();
        if (t < 8) cnt8[t] = 0;
        __syncthreads();
    }
}

// ---------- count: per-(partition,sub-slice) LDS u16x2 histogram, packed out ----------
__global__ __launch_bounds__(256) void k_cnt2(const u64* __restrict__ ebuck,
                                              const int* __restrict__ gtail,
                                              unsigned* __restrict__ cntp) {
    __shared__ unsigned h32[HPP];   // 25 KB
    int b = blockIdx.x;
    int s = b >> 3, p = b & 7;
    for (int j = threadIdx.x; j < HPP; j += 256) h32[j] = 0;
    __syncthreads();
    int pc = gtail[p];
    int len = (pc + SS - 1) / SS;
    int lo = s * len, hi = min(lo + len, pc);
    const u64* src = ebuck + (size_t)p * CAP;
    for (int i = lo + threadIdx.x; i < hi; i += 256) {
        int rl = (int)(src[i] >> 32);
        atomicAdd(&h32[rl >> 1], (rl & 1) ? 0x10000u : 1u);
    }
    __syncthreads();
    unsigned* dst = cntp + (size_t)(p * SS + s) * HPP;
    for (int j = threadIdx.x; j < HPP; j += 256) dst[j] = h32[j];
}

// ---------- fused rowdelta + scan1: counts, u16 deltas, pad8 block-scan ----------
__global__ void k_cntscan(const unsigned* __restrict__ cntp, int* __restrict__ count,
                          unsigned* __restrict__ deltap, int* __restrict__ basep,
                          int* __restrict__ bsum) {
    int b = blockIdx.x, t = threadIdx.x;
    int rp = b * 256 + t;                 // row-pair index; rows i0 = 2*rp, i0+1
    int c0 = 0, c1 = 0;
    if (rp < NN / 2) {
        int p = rp / HPP, j = rp - p * HPP;
        unsigned s0 = 0, s1 = 0;
#pragma unroll 8
        for (int c = 0; c < SS; ++c) {
            size_t o = (size_t)(p * SS + c) * HPP + j;
            unsigned v = cntp[o];
            deltap[o] = s0 | (s1 << 16);  // exclusive prefix (fits u16)
            s0 += v & 0xffffu;
            s1 += v >> 16;
        }
        c0 = (int)s0; c1 = (int)s1;
        *(int2*)(count + 2 * rp) = make_int2(c0, c1);
    }
    c0 = (c0 + 7) & ~7;                   // pad each row to multiple of 8 entries
    c1 = (c1 + 7) & ~7;
    int s = c0 + c1;
    int lane = t & 63, w = t >> 6;
    int v = s;
#pragma unroll
    for (int off = 1; off < 64; off <<= 1) {
        int u = __shfl_up(v, off, 64);
        if (lane >= off) v += u;
    }
    __shared__ int wsum[4];
    if (lane == 63) wsum[w] = v;
    __syncthreads();
    int wadd = 0;
    for (int j = 0; j < w; ++j) wadd += wsum[j];
    int incl = v + wadd;
    int excl = incl - s;
    int i0 = 2 * rp;
    if (i0 < NN) basep[i0] = excl;
    if (i0 + 1 < NN) basep[i0 + 1] = excl + c0;
    if (t == 255) bsum[b] = incl;
}

__global__ void k_scan2(int* __restrict__ bsum, int* __restrict__ base) {
    __shared__ int tmp[256];
    int t = threadIdx.x;
    int v = (t < NSCAN) ? bsum[t] : 0;
    tmp[t] = v;
    __syncthreads();
    for (int off = 1; off < 256; off <<= 1) {
        int u = (t >= off) ? tmp[t - off] : 0;
        __syncthreads();
        tmp[t] += u;
        __syncthreads();
    }
    if (t == NSCAN - 1) base[NN] = tmp[t];   // padded total = sentinel
    if (t < NSCAN) bsum[t] = tmp[t] - v;     // exclusive
}

// ---------- fill CSR; nxt = basep + bsum-chunk + u16 delta ----------
__global__ __launch_bounds__(256) void k_fill2(const u64* __restrict__ ebuck,
                                               const int* __restrict__ gtail,
                                               const unsigned* __restrict__ deltap,
                                               const int* __restrict__ basep,
                                               const int* __restrict__ bsum,
                                               unsigned* __restrict__ csre) {
    __shared__ int nxt[PSZ];   // 50 KB
    int b = blockIdx.x;
    int s = b >> 3, p = b & 7;
    const unsigned* dsrc = deltap + (size_t)(p * SS + s) * HPP;
    const int* bsrc = basep + p * PSZ;
    for (int j = threadIdx.x; j < HPP; j += 256) {
        unsigned d = dsrc[j];
        int2 bb = *(const int2*)(bsrc + 2 * j);
        int badd = bsum[(p * PSZ + 2 * j) >> 9];   // pair shares one chunk (rows even)
        nxt[2 * j] = bb.x + badd + (int)(d & 0xffffu);
        nxt[2 * j + 1] = bb.y + badd + (int)(d >> 16);
    }
    __syncthreads();
    int pc = gtail[p];
    int len = (pc + SS - 1) / SS;
    int lo = s * len, hi = min(lo + len, pc);
    const u64* src = ebuck + (size_t)p * CAP;
    for (int i = lo + threadIdx.x; i < hi; i += 256) {
        u64 en = src[i];
        int rl = (int)(en >> 32);
        int slot = atomicAdd(&nxt[rl], 1);
        csre[slot] = (unsigned)(en & 0xffffffffu);
    }
}

// ---------- degsum: dis, pad slots, and FINAL base[] (for gather) ----------
__global__ void k_degsum(const int* __restrict__ count, unsigned* __restrict__ csre,
                         const int* __restrict__ basep, const int* __restrict__ bsum,
                         int* __restrict__ base, float* __restrict__ dis) {
    int r = blockIdx.x * blockDim.x + threadIdx.x;
    if (r >= NN) return;
    int lo = basep[r] + bsum[r >> 9];
    int hip = (r == NN - 1) ? base[NN] : (basep[r + 1] + bsum[(r + 1) >> 9]);
    base[r] = lo;
    int hireal = lo + count[r];
    float s = 0.f;
    for (int e = lo; e < hireal; ++e) s += (float)(csre[e] & 0x7fffu);
    unsigned selfv = (unsigned)r << 15;
    for (int e = hireal; e < hip; ++e) csre[e] = selfv;
    dis[r] = rsqrtf(1.0f + s * (1.0f / 32767.0f));
}

// ---------- gather: 16-lane group per node; padded CSR (8); 8-deep pipeline ----------
// Output bufB is written RELU'd and PRE-SWIZZLED (chunk slot = l^(node&15)).
__global__ __launch_bounds__(256) void k_gather(const uchar* __restrict__ hW,
                                                const unsigned* __restrict__ csre,
                                                const int* __restrict__ base,
                                                const float* __restrict__ dis,
                                                const float* __restrict__ bias,
                                                ushort* __restrict__ agg) {
    int node = blockIdx.x * 16 + (threadIdx.x >> 4);
    if (node >= NN) return;
    int l = threadIdx.x & 15;
    int f = l * 8;                     // byte offset within 128B row
    int lo = base[node], hi = base[node + 1];
    float disn = dis[node];
    float wk = disn * (1.0f / 32767.0f);
    float acc[8];
    {   // self-loop (all 16 lanes of the group)
        uint2 q = *(const uint2*)(hW + (size_t)node * HH + f);
        float v[8]; unpack8_fp8(q, v);
#pragma unroll
        for (int j = 0; j < 8; ++j) acc[j] = disn * v[j];
    }
    for (int eb = lo; eb < hi; eb += 8) {
        uint4 pa = *(const uint4*)(csre + eb);
        uint4 pb = *(const uint4*)(csre + eb + 4);
        unsigned pp[8] = {pa.x, pa.y, pa.z, pa.w, pb.x, pb.y, pb.z, pb.w};
        uint2 qq[8];
#pragma unroll
        for (int j = 0; j < 8; ++j)
            qq[j] = *(const uint2*)(hW + (size_t)(pp[j] >> 15) * HH + f);
#pragma unroll
        for (int j = 0; j < 8; ++j) {
            float w = (float)(pp[j] & 0x7fffu) * wk;
            float v[8]; unpack8_fp8(qq[j], v);
#pragma unroll
            for (int k = 0; k < 8; ++k) acc[k] += w * v[k];
        }
    }
    float4 b0 = *(const float4*)(bias + f);
    float4 b1 = *(const float4*)(bias + f + 4);
    ushort o[8];
    o[0] = f2bf(fmaxf(acc[0] + b0.x, 0.f)); o[1] = f2bf(fmaxf(acc[1] + b0.y, 0.f));
    o[2] = f2bf(fmaxf(acc[2] + b0.z, 0.f)); o[3] = f2bf(fmaxf(acc[3] + b0.w, 0.f));
    o[4] = f2bf(fmaxf(acc[4] + b1.x, 0.f)); o[5] = f2bf(fmaxf(acc[5] + b1.y, 0.f));
    o[6] = f2bf(fmaxf(acc[6] + b1.z, 0.f)); o[7] = f2bf(fmaxf(acc[7] + b1.w, 0.f));
    int gsw = (l ^ (node & 15)) * 8;   // pre-swizzle for linear LDS copy
    *(uint4*)(agg + (size_t)node * HH + gsw) = *(uint4*)o;
}

// ---------- MFMA GEMM: multi-tile (TPB x 64 rows/block), K=128, bf16, fp32 acc ----------
// v6 (r13): r9's occ=17.6% (1.4 blocks/CU) = per-block staging latency paid
// serially. Now each block runs TPB=4 consecutive tiles: Ws staged ONCE,
// As double-buffered with prefetch issued before compute (latency hides under
// MFMA+epilogue). Grid 391 <= 512 resident capacity -> no tail.
// MODE 0: A fp32 (x), manual per-tile As stage  -> C_fp8 = fp8(dis*(A@W))
// MODE 1: A bf16 (pre-relu'd bufB), pipelined   -> C_fp8 = fp8(dis*(A@W))
// MODE 2: A bf16 (pre-relu'd), pipelined; heads epilogue
template <int MODE>
__global__ __launch_bounds__(256) void k_mfma(const void* __restrict__ Ain,
                                              const ushort* __restrict__ Wt,
                                              uchar* __restrict__ C,
                                              const float* __restrict__ dis,
                                              const float* __restrict__ b1,
                                              const float* __restrict__ w2v,
                                              const float* __restrict__ b2,
                                              const int* __restrict__ ready,
                                              float* __restrict__ logits,
                                              float* __restrict__ meansum,
                                              unsigned* __restrict__ maxenc,
                                              unsigned* __restrict__ lmaxenc, int n) {
    __shared__ ushort Ws[128 * HH];                    // 32 KB
    __shared__ __align__(16) ushort As[2][64 * HH];    // 2 x 16 KB (dbuf)
    __shared__ __align__(16) uchar Cs[64 * 144];       // 9.2 KB transpose tile
    __shared__ int rdy[64];
    __shared__ float xs[128];
    __shared__ float xmf[128];
    __shared__ unsigned slmax;
    const int t = threadIdx.x;
    const int wv = t >> 6, ln = t & 63;

    // ---- stage Ws once (async linear copy of pre-swizzled Wt) ----
    {
        const char* wsb = (const char*)Wt;
        char* wdb = (char*)Ws;
#pragma unroll
        for (int i = 0; i < 8; ++i) {
            int blk = wv * 8 + i;
            gl2lds16(wsb + blk * 1024 + ln * 16, wdb + blk * 1024);
        }
    }
    if (MODE != 0) {
        // prefetch As for tile 0
        const char* asb = (const char*)Ain + (size_t)(blockIdx.x * TPB) * 64 * HH * 2;
        char* adb = (char*)As[0];
#pragma unroll
        for (int i = 0; i < 4; ++i) {
            int blk = wv * 4 + i;
            gl2lds16(asb + blk * 1024 + ln * 16, adb + blk * 1024);
        }
    }
    if (MODE == 2 && t == 0) slmax = ENC_NEG_INF;
    __syncthreads();

    const int cl = ln & 15;
    const int kq = ln >> 4;
    const int m0 = wv * 16;

    for (int tt = 0; tt < TPB; ++tt) {
        const int rb = (blockIdx.x * TPB + tt) * 64;
        const ushort* Asc = As[MODE == 0 ? 0 : (tt & 1)];

        if (MODE == 0) {
            // manual stage As (loop-end/entry barrier ensured previous reads done)
#pragma unroll
            for (int i = 0; i < 4; ++i) {
                int m = i * 16 + (t >> 4);
                int k = (t & 15) * 8;
                ushort pk[8];
                const float* Af = (const float*)Ain;
                float4 v0 = make_float4(0.f, 0.f, 0.f, 0.f), v1 = v0;
                if (rb + m < n) {
                    const float* src = Af + (size_t)(rb + m) * HH + k;
                    v0 = *(const float4*)src;
                    v1 = *(const float4*)(src + 4);
                }
                pk[0] = f2bf(v0.x); pk[1] = f2bf(v0.y); pk[2] = f2bf(v0.z); pk[3] = f2bf(v0.w);
                pk[4] = f2bf(v1.x); pk[5] = f2bf(v1.y); pk[6] = f2bf(v1.z); pk[7] = f2bf(v1.w);
                int gsw = (t & 15) ^ (m & 15);
                *(uint4*)(As[0] + m * HH + gsw * 8) = *(uint4*)pk;
            }
        } else if (tt + 1 < TPB) {
            // issue prefetch of next tile into the other buffer (consumed after
            // the loop-end barrier; latency hides under MFMA + epilogue)
            const char* asb = (const char*)Ain + (size_t)(rb + 64) * HH * 2;
            char* adb = (char*)As[(tt + 1) & 1];
#pragma unroll
            for (int i = 0; i < 4; ++i) {
                int blk = wv * 4 + i;
                gl2lds16(asb + blk * 1024 + ln * 16, adb + blk * 1024);
            }
        }
        if (MODE == 2) {
            if (t < 64) rdy[t] = (rb + t < n) ? ready[rb + t] : 0;
        }
        __syncthreads();   // MODE0: stage visible; MODE2: rdy visible; all: dbuf safe

        f32x4 acc[8];
#pragma unroll
        for (int c = 0; c < 8; ++c) acc[c] = (f32x4){0.f, 0.f, 0.f, 0.f};

#pragma unroll
        for (int kk = 0; kk < 4; ++kk) {
            int g = kk * 4 + kq;
            bf16x8 bfr = *(const bf16x8*)(Asc + (m0 + cl) * HH + ((g ^ cl) * 8));
#pragma unroll
            for (int c = 0; c < 8; ++c) {
                bf16x8 afr = *(const bf16x8*)(Ws + (c * 16 + cl) * HH + ((g ^ cl) * 8));
                acc[c] = __builtin_amdgcn_mfma_f32_16x16x32_bf16(afr, bfr, acc[c], 0, 0, 0);
            }
        }

        const int node = rb + m0 + cl;
        if (MODE < 2) {
            // full-line C store via LDS transpose (144B pitch = 2-way banks)
            float d = (node < n) ? dis[node] : 0.f;
#pragma unroll
            for (int c = 0; c < 8; ++c) {
                unsigned u = __builtin_amdgcn_cvt_pk_fp8_f32(acc[c][0] * d, acc[c][1] * d, 0u, false);
                u = __builtin_amdgcn_cvt_pk_fp8_f32(acc[c][2] * d, acc[c][3] * d, u, true);
                *(unsigned*)(Cs + (m0 + cl) * 144 + c * 16 + kq * 4) = u;
            }
            __syncthreads();
            int row = t >> 2, off = (t & 3) * 32;
            if (rb + row < n) {
                uint4 q0 = *(const uint4*)(Cs + row * 144 + off);
                uint4 q1 = *(const uint4*)(Cs + row * 144 + off + 16);
                uchar* dst = C + (size_t)(rb + row) * HH + off;
                *(uint4*)dst = q0;
                *(uint4*)(dst + 16) = q1;
            }
        } else {
            // heads epilogue
            float s = 0.f;
#pragma unroll
            for (int c = 0; c < 8; ++c) {
                float4 bb = *(const float4*)(b1 + c * 16 + kq * 4);
                float4 ww = *(const float4*)(w2v + c * 16 + kq * 4);
                s += fmaxf(acc[c][0] + bb.x, 0.f) * ww.x;
                s += fmaxf(acc[c][1] + bb.y, 0.f) * ww.y;
                s += fmaxf(acc[c][2] + bb.z, 0.f) * ww.z;
                s += fmaxf(acc[c][3] + bb.w, 0.f) * ww.w;
            }
            s += __shfl_xor(s, 16, 64);
            s += __shfl_xor(s, 32, 64);
            unsigned mylmax = ENC_NEG_INF;
            if (kq == 0 && node < n) {
                float lg = s + b2[0];
                logits[node] = lg;
                if (rdy[m0 + cl] > 0) mylmax = encf(lg);
            }
            if (mylmax != ENC_NEG_INF) atomicMax(&slmax, mylmax);

            // mean / masked-max: 256 threads, 2 row-halves + LDS combine
            int lim = min(64, n - rb);
            {
                int f = t & 127, h = t >> 7;
                int gf = f >> 3, fo = f & 7;
                float sum = 0.f, mx = -3.4e38f;
                int mlo = h * 32, mhi = min(lim, mlo + 32);
                for (int m = mlo; m < mhi; ++m) {
                    float v = bf2f(Asc[m * HH + ((gf ^ (m & 15)) * 8) + fo]);
                    sum += v;
                    if (rdy[m] > 0) mx = fmaxf(mx, v);
                }
                if (h == 0) { xs[f] = sum; xmf[f] = mx; }
                __syncthreads();
                if (h == 1 && lim > 0) {
                    sum += xs[f];
                    mx = fmaxf(mx, xmf[f]);
                    int rep = blockIdx.x & (NREP - 1);
                    atomicAdd(&meansum[rep * HH + f], sum);
                    if (mx > -3.0e38f) atomicMax(&maxenc[rep * HH + f], encf(mx));
                }
            }
        }
        __syncthreads();   // epilogue LDS reads done; prefetch landed (vmcnt drain)
    }
    if (MODE == 2 && t == 0 && slmax != ENC_NEG_INF) atomicMax(lmaxenc, slmax);
}

// ---------- small finalize: fc, pass-MLP, v, global max M ----------
__global__ void k_fin1(const float* __restrict__ meansum, const unsigned* __restrict__ maxenc,
                       const unsigned* __restrict__ lmaxenc,
                       const float* __restrict__ val_w, const float* __restrict__ val_b,
                       const float* __restrict__ pe, const float* __restrict__ cl_w,
                       const float* __restrict__ cl_b, const float* __restrict__ pw1,
                       const float* __restrict__ pb1, const float* __restrict__ pw2,
                       const float* __restrict__ pb2, float* __restrict__ scal,
                       float* __restrict__ d_out) {
    __shared__ float xp[144];
    __shared__ float msum[HH];
    __shared__ float zp[HH];
    int t = threadIdx.x;
    if (t < HH) {
        float s = 0.f;
        unsigned mx = ENC_NEG_INF;
        for (int r = 0; r < NREP; ++r) {
            s += meansum[r * HH + t];
            unsigned e = maxenc[r * HH + t];
            if (e > mx) mx = e;
        }
        msum[t] = s;
        xp[t] = decf(mx);
    } else if (t < 144) {
        int c = t - HH;
        float s = cl_b[c];
        for (int k = 0; k < 30; ++k) s += pe[k] * cl_w[k * 16 + c];
        xp[t] = s;
    }
    __syncthreads();
    if (t < HH) {
        float s = pb1[t];
        for (int k = 0; k < 144; ++k) s += xp[k] * pw1[k * HH + t];
        zp[t] = fmaxf(s, 0.f);
    }
    __syncthreads();
    if (t < 64) {
        float s1 = zp[t] * pw2[t] + zp[t + 64] * pw2[t + 64];
        float s2 = msum[t] * val_w[t] + msum[t + 64] * val_w[t + 64];
#pragma unroll
        for (int off = 32; off > 0; off >>= 1) {
            s1 += __shfl_xor(s1, off, 64);
            s2 += __shfl_xor(s2, off, 64);
        }
        if (t == 0) {
            float xpass = s1 + pb2[0];
            float v = s2 * (1.0f / NN) + val_b[0];
            float M = fmaxf(decf(lmaxenc[0]), xpass);
            scal[0] = M;
            scal[1] = expf(xpass - M);
            d_out[NN + 1] = v;
        }
    }
}

// ---------- exp pass: unnormalized probs + sum ----------
__global__ __launch_bounds__(256) void k_exp(const float* __restrict__ logits,
                                             const int* __restrict__ ready,
                                             const float* __restrict__ scal,
                                             float* __restrict__ d_out,
                                             float* __restrict__ esum) {
    __shared__ float warr[4];
    int t = threadIdx.x;
    int i = blockIdx.x * 256 + t;
    float M = scal[0];
    float p = 0.f;
    if (i < NN) {
        if (ready[i] > 0) p = expf(logits[i] - M);
        d_out[i] = p;
    }
    float s = p;
#pragma unroll
    for (int off = 32; off > 0; off >>= 1) s += __shfl_xor(s, off, 64);
    if ((t & 63) == 0) warr[t >> 6] = s;
    __syncthreads();
    if (t == 0) atomicAdd(esum, warr[0] + warr[1] + warr[2] + warr[3]);
}

// ---------- normalize ----------
__global__ void k_scale(const float* __restrict__ esum, const float* __restrict__ scal,
                        float* __restrict__ d_out) {
    int i = blockIdx.x * blockDim.x + threadIdx.x;
    float inv = 1.0f / (esum[0] + scal[1]);
    if (i < NN) d_out[i] *= inv;
    else if (i == NN) d_out[NN] = scal[1] * inv;
}

extern "C" void kernel_launch(void* const* d_in, const int* in_sizes, int n_in,
                              void* d_out, int out_size, void* d_ws, size_t ws_size,
                              hipStream_t stream) {
    const float* x      = (const float*)d_in[0];
    const int*   edges  = (const int*)d_in[1];
    const float* eattr  = (const float*)d_in[2];
    const int*   ready  = (const int*)d_in[3];
    const float* pe     = (const float*)d_in[4];
    const float* gcn_w  = (const float*)d_in[5];
    const float* gcn_b  = (const float*)d_in[6];
    const float* mlp_w1 = (const float*)d_in[7];
    const float* mlp_b1 = (const float*)d_in[8];
    const float* mlp_w2 = (const float*)d_in[9];
    const float* mlp_b2 = (const float*)d_in[10];
    const float* val_w  = (const float*)d_in[11];
    const float* val_b  = (const float*)d_in[12];
    const float* cl_w   = (const float*)d_in[13];
    const float* cl_b   = (const float*)d_in[14];
    const float* pw1    = (const float*)d_in[15];
    const float* pb1    = (const float*)d_in[16];
    const float* pw2    = (const float*)d_in[17];
    const float* pb2    = (const float*)d_in[18];

    const int* rows = edges;
    const int* cols = edges + EE;

    // workspace carving (256B-aligned slices)
    char* P = (char*)d_ws;
    size_t off = 0;
    auto carve = [&](size_t bytes) {
        off = (off + 255) & ~(size_t)255;
        void* p = P + off;
        off += bytes;
        return p;
    };
    float* dis     = (float*)carve(NN * 4);
    float* logits  = (float*)carve(NN * 4);
    int*   count   = (int*)carve(NN * 4);
    int*   basep   = (int*)carve(NN * 4);          // partial scan (pre block-offset)
    int*   base    = (int*)carve((NN + 1) * 4);    // final row starts (degsum-written)
    int*   bsum    = (int*)carve(256 * 4);
    ushort* bufB   = (ushort*)carve((size_t)(NN + 256) * HH * 2);  // bf16 (+over-read pad)
    uchar* bufH    = (uchar*)carve((size_t)NN * HH);        // fp8 (gemm out / gather in)
    unsigned* csre = (unsigned*)carve((size_t)(EE + 8 * NN) * 4);  // padded CSR entries
    u64*   ebuck   = (u64*)carve((size_t)8 * CAP * 8);      // partition-major streams
    float* meansum = (float*)carve(NREP * HH * 4);
    unsigned* maxenc = (unsigned*)carve(NREP * HH * 4);
    unsigned* lmaxenc = (unsigned*)carve(4);
    float* esum    = (float*)carve(4);
    float* scal    = (float*)carve(8);
    int*   gtail   = (int*)carve(8 * 4);
    ushort* wt     = (ushort*)carve(3 * HH * HH * 2);

    // aliases (lifetime-disjoint with bufB, which k_gather first writes after fill2):
    unsigned* cntp   = (unsigned*)bufB;
    unsigned* deltap = (unsigned*)bufB + (size_t)8 * SS * HPP;

    float* out = (float*)d_out;

    const int nb = (NN + 255) / 256;
    const int gb4 = (NN + TPB * 64 - 1) / (TPB * 64);   // mfma: 4 tiles/block = 391
    const int ab = (NN + 15) / 16;          // gather: 16-lane group per node
    const int pb = 8 * SS;                  // cnt2/fill2 blocks

    k_setup<<<(3 * HH * HH + 255) / 256, 256, 0, stream>>>(meansum, maxenc, lmaxenc, esum,
                                                           gtail, gcn_w, gcn_w + HH * HH,
                                                           mlp_w1, wt);

    // CSR build: bucket -> cnt2 -> cntscan -> scan2 -> fill2 -> degsum
    k_bucket<<<NBB, 256, 0, stream>>>(rows, cols, eattr, gtail, ebuck);
    k_cnt2<<<pb, 256, 0, stream>>>(ebuck, gtail, cntp);
    k_cntscan<<<NSCAN, 256, 0, stream>>>(cntp, count, deltap, basep, bsum);
    k_scan2<<<1, 256, 0, stream>>>(bsum, base);
    k_fill2<<<pb, 256, 0, stream>>>(ebuck, gtail, deltap, basep, bsum, csre);
    k_degsum<<<nb, 256, 0, stream>>>(count, csre, basep, bsum, base, dis);

    // layer 0
    k_mfma<0><<<gb4, 256, 0, stream>>>(x, wt, bufH, dis, nullptr, nullptr, nullptr, nullptr,
                                       nullptr, nullptr, nullptr, nullptr, NN);
    k_gather<<<ab, 256, 0, stream>>>(bufH, csre, base, dis, gcn_b, bufB);

    // layer 1
    k_mfma<1><<<gb4, 256, 0, stream>>>(bufB, wt + HH * HH, bufH, dis, nullptr, nullptr, nullptr,
                                       nullptr, nullptr, nullptr, nullptr, nullptr, NN);
    k_gather<<<ab, 256, 0, stream>>>(bufH, csre, base, dis, gcn_b + HH, bufB);

    // heads
    k_mfma<2><<<gb4, 256, 0, stream>>>(bufB, wt + 2 * HH * HH, nullptr, nullptr, mlp_b1, mlp_w2,
                                       mlp_b2, ready, logits, meansum, maxenc, lmaxenc, NN);
    k_fin1<<<1, 256, 0, stream>>>(meansum, maxenc, lmaxenc, val_w, val_b, pe, cl_w, cl_b,
                                  pw1, pb1, pw2, pb2, scal, out);
    k_exp<<<nb, 256, 0, stream>>>(logits, ready, scal, out, esum);
    k_scale<<<(NN + 1 + 255) / 256, 256, 0, stream>>>(esum, scal, out);
}

// Round 14
// 329.264 us; speedup vs baseline: 1.0122x; 1.0122x over previous
//
#include <hip/hip_runtime.h>
#include <cstdint>

#define NN 100000
#define EE 1600000
#define HH 128
#define NREP 64
#define PSZ (NN / 8)                 // 12500 rows per partition
#define HPP (PSZ / 2)                // 6250 row-pairs per partition
#define SS 32                        // sub-slices per partition (r14: 64->32, halves slice-staging traffic)
#define CAP 300000                   // per-partition bucket capacity (entries)
#define NBB 500                      // bucket blocks
#define BCH 3200                     // edges per bucket block (500*3200 = EE)
#define SCAN_CHUNK 512
#define NSCAN ((NN + SCAN_CHUNK - 1) / SCAN_CHUNK)   // 196

typedef unsigned long long u64;
typedef unsigned short ushort;
typedef unsigned char uchar;
typedef __attribute__((ext_vector_type(8))) short bf16x8;
typedef __attribute__((ext_vector_type(4))) float f32x4;
typedef __attribute__((ext_vector_type(2))) float f32x2;

// ---------- async global->LDS 16B copy (gfx950) ----------
__device__ __forceinline__ void gl2lds16(const void* g, void* l) {
#if __has_builtin(__builtin_amdgcn_global_load_lds)
    __builtin_amdgcn_global_load_lds(
        (const __attribute__((address_space(1))) unsigned int*)g,
        (__attribute__((address_space(3))) unsigned int*)l, 16, 0, 0);
#else
    *(uint4*)l = *(const uint4*)g;
#endif
}

// ---------- bf16 helpers (RNE, finite values) ----------
__device__ __forceinline__ ushort f2bf(float x) {
    union { float f; unsigned u; } v; v.f = x;
    unsigned r = v.u + 0x7fffu + ((v.u >> 16) & 1u);
    return (ushort)(r >> 16);
}
__device__ __forceinline__ float bf2f(unsigned h16) {
    union { unsigned u; float f; } v; v.u = h16 << 16; return v.f;
}

// ---------- fp8 e4m3 helpers (HW cvt) ----------
__device__ __forceinline__ uchar f2fp8(float a) {
    return (uchar)(__builtin_amdgcn_cvt_pk_fp8_f32(a, a, 0, false) & 0xff);
}
__device__ __forceinline__ void unpack8_fp8(uint2 q, float* v) {
    f32x2 a = __builtin_amdgcn_cvt_pk_f32_fp8(q.x, false);
    f32x2 b = __builtin_amdgcn_cvt_pk_f32_fp8(q.x, true);
    f32x2 c = __builtin_amdgcn_cvt_pk_f32_fp8(q.y, false);
    f32x2 d = __builtin_amdgcn_cvt_pk_f32_fp8(q.y, true);
    v[0] = a[0]; v[1] = a[1]; v[2] = b[0]; v[3] = b[1];
    v[4] = c[0]; v[5] = c[1]; v[6] = d[0]; v[7] = d[1];
}

// ---------- monotone float<->uint encoding for atomicMax on floats ----------
__device__ __forceinline__ unsigned encf(float f) {
    int b = __float_as_int(f);
    return (b >= 0) ? ((unsigned)b | 0x80000000u) : ~(unsigned)b;
}
__device__ __forceinline__ float decf(unsigned u) {
    return (u & 0x80000000u) ? __int_as_float((int)(u & 0x7fffffffu))
                             : __int_as_float((int)(~u));
}
#define ENC_NEG_INF 0x007FFFFFu  // encf(-inf)

// ---------- setup: init accumulators + pre-transpose weights to bf16 ----------
// wt is stored PRE-SWIZZLED: chunk g of row n lands at slot g^(n&15).
__global__ void k_setup(float* __restrict__ meansum, unsigned* __restrict__ maxenc,
                        unsigned* __restrict__ lmaxenc, float* __restrict__ esum,
                        int* __restrict__ gtail,
                        const float* __restrict__ w0, const float* __restrict__ w1,
                        const float* __restrict__ w2, ushort* __restrict__ wt) {
    int idx = blockIdx.x * blockDim.x + threadIdx.x;
    if (idx < NREP * HH) { meansum[idx] = 0.f; maxenc[idx] = ENC_NEG_INF; }
    if (idx < 8) gtail[idx] = 0;
    if (idx == 0) { lmaxenc[0] = ENC_NEG_INF; esum[0] = 0.f; }
    if (idx < 3 * HH * HH) {
        int mat = idx >> 14;
        int e = idx & 16383;
        int n = e >> 7, k = e & 127;
        int g = k >> 3, el = k & 7;
        const float* src = (mat == 0) ? w0 : (mat == 1) ? w1 : w2;
        int pos = (mat << 14) | (n << 7) | (((g ^ (n & 15)) << 3) | el);
        wt[pos] = f2bf(src[k * HH + n]);
    }
}

// ---------- bucket: split edges into 8 partition-major packed streams ----------
// entry: (rlocal << 32) | (col << 15) | q15
// NOTE: plain LDS atomics. Ballot-aggregation variant (r5) REGRESSED +14us.
__global__ __launch_bounds__(256) void k_bucket(const int* __restrict__ rows,
                                                const int* __restrict__ cols,
                                                const float* __restrict__ ea,
                                                int* __restrict__ gtail,
                                                u64* __restrict__ ebuck) {
    __shared__ u64 buf[8][1024];   // 64 KB
    __shared__ int cnt8[8];
    __shared__ int rsv[8];
    int t = threadIdx.x;
    if (t < 8) cnt8[t] = 0;
    __syncthreads();
    int e0 = blockIdx.x * BCH;
    int e1 = e0 + BCH;
    for (int ebase = e0; ebase < e1; ebase += 1024) {
        int e = ebase + t * 4;
        if (e < e1) {
            int4 r4 = *(const int4*)(rows + e);
            int4 c4 = *(const int4*)(cols + e);
            float4 a4 = *(const float4*)(ea + e);
            int rr[4] = {r4.x, r4.y, r4.z, r4.w};
            int cc[4] = {c4.x, c4.y, c4.z, c4.w};
            float aa[4] = {a4.x, a4.y, a4.z, a4.w};
#pragma unroll
            for (int j = 0; j < 4; ++j) {
                int p = rr[j] / PSZ;
                int rl = rr[j] - p * PSZ;
                unsigned q = (unsigned)(aa[j] * 32767.0f + 0.5f);
                u64 en = ((u64)rl << 32) | (u64)(((unsigned)cc[j] << 15) | q);
                int idx = atomicAdd(&cnt8[p], 1);
                buf[p][idx] = en;
            }
        }
        __syncthreads();
        if (t < 8) rsv[t] = atomicAdd(&gtail[t], cnt8[t]);
        __syncthreads();
#pragma unroll
        for (int p = 0; p < 8; ++p) {
            int nn = cnt8[p], oo = rsv[p];
            u64* dst = ebuck + (size_t)p * CAP + oo;
            for (int j = t; j < nn; j += 256) dst[j] = buf[p][j];
        }
        __syncthreads();
        if (t < 8) cnt8[t] = 0;
        __syncthreads();
    }
}

// ---------- count: per-(partition,sub-slice) LDS u16x2 histogram, packed out ----------
__global__ __launch_bounds__(256) void k_cnt2(const u64* __restrict__ ebuck,
                                              const int* __restrict__ gtail,
                                              unsigned* __restrict__ cntp) {
    __shared__ unsigned h32[HPP];   // 25 KB
    int b = blockIdx.x;
    int s = b >> 3, p = b & 7;
    for (int j = threadIdx.x; j < HPP; j += 256) h32[j] = 0;
    __syncthreads();
    int pc = gtail[p];
    int len = (pc + SS - 1) / SS;
    int lo = s * len, hi = min(lo + len, pc);
    const u64* src = ebuck + (size_t)p * CAP;
    for (int i = lo + threadIdx.x; i < hi; i += 256) {
        int rl = (int)(src[i] >> 32);
        atomicAdd(&h32[rl >> 1], (rl & 1) ? 0x10000u : 1u);
    }
    __syncthreads();
    unsigned* dst = cntp + (size_t)(p * SS + s) * HPP;
    for (int j = threadIdx.x; j < HPP; j += 256) dst[j] = h32[j];
}

// ---------- fused rowdelta + scan1: counts, u16 deltas, pad8 block-scan ----------
__global__ void k_cntscan(const unsigned* __restrict__ cntp, int* __restrict__ count,
                          unsigned* __restrict__ deltap, int* __restrict__ basep,
                          int* __restrict__ bsum) {
    int b = blockIdx.x, t = threadIdx.x;
    int rp = b * 256 + t;                 // row-pair index; rows i0 = 2*rp, i0+1
    int c0 = 0, c1 = 0;
    if (rp < NN / 2) {
        int p = rp / HPP, j = rp - p * HPP;
        unsigned s0 = 0, s1 = 0;
#pragma unroll 8
        for (int c = 0; c < SS; ++c) {
            size_t o = (size_t)(p * SS + c) * HPP + j;
            unsigned v = cntp[o];
            deltap[o] = s0 | (s1 << 16);  // exclusive prefix (fits u16)
            s0 += v & 0xffffu;
            s1 += v >> 16;
        }
        c0 = (int)s0; c1 = (int)s1;
        *(int2*)(count + 2 * rp) = make_int2(c0, c1);
    }
    c0 = (c0 + 7) & ~7;                   // pad each row to multiple of 8 entries
    c1 = (c1 + 7) & ~7;
    int s = c0 + c1;
    int lane = t & 63, w = t >> 6;
    int v = s;
#pragma unroll
    for (int off = 1; off < 64; off <<= 1) {
        int u = __shfl_up(v, off, 64);
        if (lane >= off) v += u;
    }
    __shared__ int wsum[4];
    if (lane == 63) wsum[w] = v;
    __syncthreads();
    int wadd = 0;
    for (int j = 0; j < w; ++j) wadd += wsum[j];
    int incl = v + wadd;
    int excl = incl - s;
    int i0 = 2 * rp;
    if (i0 < NN) basep[i0] = excl;
    if (i0 + 1 < NN) basep[i0 + 1] = excl + c0;
    if (t == 255) bsum[b] = incl;
}

__global__ void k_scan2(int* __restrict__ bsum, int* __restrict__ base) {
    __shared__ int tmp[256];
    int t = threadIdx.x;
    int v = (t < NSCAN) ? bsum[t] : 0;
    tmp[t] = v;
    __syncthreads();
    for (int off = 1; off < 256; off <<= 1) {
        int u = (t >= off) ? tmp[t - off] : 0;
        __syncthreads();
        tmp[t] += u;
        __syncthreads();
    }
    if (t == NSCAN - 1) base[NN] = tmp[t];   // padded total = sentinel
    if (t < NSCAN) bsum[t] = tmp[t] - v;     // exclusive
}

// ---------- fill CSR; nxt = basep + bsum-chunk + u16 delta ----------
__global__ __launch_bounds__(256) void k_fill2(const u64* __restrict__ ebuck,
                                               const int* __restrict__ gtail,
                                               const unsigned* __restrict__ deltap,
                                               const int* __restrict__ basep,
                                               const int* __restrict__ bsum,
                                               unsigned* __restrict__ csre) {
    __shared__ int nxt[PSZ];   // 50 KB
    int b = blockIdx.x;
    int s = b >> 3, p = b & 7;
    const unsigned* dsrc = deltap + (size_t)(p * SS + s) * HPP;
    const int* bsrc = basep + p * PSZ;
    for (int j = threadIdx.x; j < HPP; j += 256) {
        unsigned d = dsrc[j];
        int2 bb = *(const int2*)(bsrc + 2 * j);
        int badd = bsum[(p * PSZ + 2 * j) >> 9];   // pair shares one chunk (rows even)
        nxt[2 * j] = bb.x + badd + (int)(d & 0xffffu);
        nxt[2 * j + 1] = bb.y + badd + (int)(d >> 16);
    }
    __syncthreads();
    int pc = gtail[p];
    int len = (pc + SS - 1) / SS;
    int lo = s * len, hi = min(lo + len, pc);
    const u64* src = ebuck + (size_t)p * CAP;
    for (int i = lo + threadIdx.x; i < hi; i += 256) {
        u64 en = src[i];
        int rl = (int)(en >> 32);
        int slot = atomicAdd(&nxt[rl], 1);
        csre[slot] = (unsigned)(en & 0xffffffffu);
    }
}

// ---------- degsum: dis, pad slots, and FINAL base[] (for gather) ----------
__global__ void k_degsum(const int* __restrict__ count, unsigned* __restrict__ csre,
                         const int* __restrict__ basep, const int* __restrict__ bsum,
                         int* __restrict__ base, float* __restrict__ dis) {
    int r = blockIdx.x * blockDim.x + threadIdx.x;
    if (r >= NN) return;
    int lo = basep[r] + bsum[r >> 9];
    int hip = (r == NN - 1) ? base[NN] : (basep[r + 1] + bsum[(r + 1) >> 9]);
    base[r] = lo;
    int hireal = lo + count[r];
    float s = 0.f;
    for (int e = lo; e < hireal; ++e) s += (float)(csre[e] & 0x7fffu);
    unsigned selfv = (unsigned)r << 15;
    for (int e = hireal; e < hip; ++e) csre[e] = selfv;
    dis[r] = rsqrtf(1.0f + s * (1.0f / 32767.0f));
}

// ---------- gather: 16-lane group per node; padded CSR (8); 8-deep pipeline ----------
// Output bufB is written RELU'd and PRE-SWIZZLED (chunk slot = l^(node&15)).
__global__ __launch_bounds__(256) void k_gather(const uchar* __restrict__ hW,
                                                const unsigned* __restrict__ csre,
                                                const int* __restrict__ base,
                                                const float* __restrict__ dis,
                                                const float* __restrict__ bias,
                                                ushort* __restrict__ agg) {
    int node = blockIdx.x * 16 + (threadIdx.x >> 4);
    if (node >= NN) return;
    int l = threadIdx.x & 15;
    int f = l * 8;                     // byte offset within 128B row
    int lo = base[node], hi = base[node + 1];
    float disn = dis[node];
    float wk = disn * (1.0f / 32767.0f);
    float acc[8];
    {   // self-loop (all 16 lanes of the group)
        uint2 q = *(const uint2*)(hW + (size_t)node * HH + f);
        float v[8]; unpack8_fp8(q, v);
#pragma unroll
        for (int j = 0; j < 8; ++j) acc[j] = disn * v[j];
    }
    for (int eb = lo; eb < hi; eb += 8) {
        uint4 pa = *(const uint4*)(csre + eb);
        uint4 pb = *(const uint4*)(csre + eb + 4);
        unsigned pp[8] = {pa.x, pa.y, pa.z, pa.w, pb.x, pb.y, pb.z, pb.w};
        uint2 qq[8];
#pragma unroll
        for (int j = 0; j < 8; ++j)
            qq[j] = *(const uint2*)(hW + (size_t)(pp[j] >> 15) * HH + f);
#pragma unroll
        for (int j = 0; j < 8; ++j) {
            float w = (float)(pp[j] & 0x7fffu) * wk;
            float v[8]; unpack8_fp8(qq[j], v);
#pragma unroll
            for (int k = 0; k < 8; ++k) acc[k] += w * v[k];
        }
    }
    float4 b0 = *(const float4*)(bias + f);
    float4 b1 = *(const float4*)(bias + f + 4);
    ushort o[8];
    o[0] = f2bf(fmaxf(acc[0] + b0.x, 0.f)); o[1] = f2bf(fmaxf(acc[1] + b0.y, 0.f));
    o[2] = f2bf(fmaxf(acc[2] + b0.z, 0.f)); o[3] = f2bf(fmaxf(acc[3] + b0.w, 0.f));
    o[4] = f2bf(fmaxf(acc[4] + b1.x, 0.f)); o[5] = f2bf(fmaxf(acc[5] + b1.y, 0.f));
    o[6] = f2bf(fmaxf(acc[6] + b1.z, 0.f)); o[7] = f2bf(fmaxf(acc[7] + b1.w, 0.f));
    int gsw = (l ^ (node & 15)) * 8;   // pre-swizzle for linear LDS copy
    *(uint4*)(agg + (size_t)node * HH + gsw) = *(uint4*)o;
}

// ---------- MFMA GEMM: 64x128 tile, K=128, bf16 inputs, fp32 acc ----------
// r12-measured best config (330.6us total). Multi-tile pipelined variant (r13)
// was +2.7us — reverted. Ws/As async-staged from pre-swizzled globals; C stored
// as full 128B lines via LDS transpose; MODE2 stats use all 256 threads.
// MODE 0: A fp32 (x), manual As stage  -> C_fp8 = fp8(dis*(A@W))
// MODE 1: A bf16 (pre-relu'd bufB)     -> C_fp8 = fp8(dis*(A@W))
// MODE 2: A bf16 (pre-relu'd); heads epilogue
template <int MODE>
__global__ __launch_bounds__(256) void k_mfma(const void* __restrict__ Ain,
                                              const ushort* __restrict__ Wt,
                                              uchar* __restrict__ C,
                                              const float* __restrict__ dis,
                                              const float* __restrict__ b1,
                                              const float* __restrict__ w2v,
                                              const float* __restrict__ b2,
                                              const int* __restrict__ ready,
                                              float* __restrict__ logits,
                                              float* __restrict__ meansum,
                                              unsigned* __restrict__ maxenc,
                                              unsigned* __restrict__ lmaxenc, int n) {
    __shared__ __align__(16) ushort As[64 * HH];  // 16 KB (mode<2: reused as C-tile)
    __shared__ ushort Ws[128 * HH];               // 32 KB
    __shared__ int rdy[64];
    __shared__ float xs[128];
    __shared__ float xmf[128];
    __shared__ unsigned slmax;
    const int t = threadIdx.x;
    const int rb = blockIdx.x * 64;
    const int wv = t >> 6, ln = t & 63;

    // ---- async stage Ws: linear 32KB copy of pre-swizzled Wt ----
    {
        const char* wsb = (const char*)Wt;
        char* wdb = (char*)Ws;
#pragma unroll
        for (int i = 0; i < 8; ++i) {
            int blk = wv * 8 + i;               // 32 x 1KB wave-chunks
            gl2lds16(wsb + blk * 1024 + ln * 16, wdb + blk * 1024);
        }
    }
    if (MODE != 0) {
        // ---- async stage As: linear 16KB copy of pre-swizzled, pre-relu'd bufB ----
        const char* asb = (const char*)Ain + (size_t)rb * HH * 2;
        char* adb = (char*)As;
#pragma unroll
        for (int i = 0; i < 4; ++i) {
            int blk = wv * 4 + i;               // 16 x 1KB wave-chunks
            gl2lds16(asb + blk * 1024 + ln * 16, adb + blk * 1024);
        }
    } else {
        // ---- manual stage As from fp32 x (cvt + swizzled ds_write) ----
#pragma unroll
        for (int i = 0; i < 4; ++i) {
            int m = i * 16 + (t >> 4);
            int k = (t & 15) * 8;
            ushort pk[8];
            const float* Af = (const float*)Ain;
            float4 v0 = make_float4(0.f, 0.f, 0.f, 0.f), v1 = v0;
            if (rb + m < n) {
                const float* src = Af + (size_t)(rb + m) * HH + k;
                v0 = *(const float4*)src;
                v1 = *(const float4*)(src + 4);
            }
            pk[0] = f2bf(v0.x); pk[1] = f2bf(v0.y); pk[2] = f2bf(v0.z); pk[3] = f2bf(v0.w);
            pk[4] = f2bf(v1.x); pk[5] = f2bf(v1.y); pk[6] = f2bf(v1.z); pk[7] = f2bf(v1.w);
            int gsw = (t & 15) ^ (m & 15);
            *(uint4*)(As + m * HH + gsw * 8) = *(uint4*)pk;
        }
    }
    if (MODE == 2) {
        if (t < 64) rdy[t] = (rb + t < n) ? ready[rb + t] : 0;
        if (t == 0) slmax = ENC_NEG_INF;
    }
    __syncthreads();

    const int cl = ln & 15;         // node-within-wave-tile / Ws row low bits
    const int kq = ln >> 4;         // k quad
    const int m0 = wv * 16;

    f32x4 acc[8];
#pragma unroll
    for (int c = 0; c < 8; ++c) acc[c] = (f32x4){0.f, 0.f, 0.f, 0.f};

#pragma unroll
    for (int kk = 0; kk < 4; ++kk) {
        int g = kk * 4 + kq;
        bf16x8 bfr = *(const bf16x8*)(As + (m0 + cl) * HH + ((g ^ cl) * 8));
#pragma unroll
        for (int c = 0; c < 8; ++c) {
            bf16x8 afr = *(const bf16x8*)(Ws + (c * 16 + cl) * HH + ((g ^ cl) * 8));
            // D[row=feature kq*4+r within c-block][col=node cl]
            acc[c] = __builtin_amdgcn_mfma_f32_16x16x32_bf16(afr, bfr, acc[c], 0, 0, 0);
        }
    }

    const int node = rb + m0 + cl;
    if (MODE < 2) {
        // ---- full-line C store via LDS transpose (kills write-allocate) ----
        float d = (node < n) ? dis[node] : 0.f;
        uchar* Cs = (uchar*)As;     // 64 rows x 144B pitch (9.2 KB, overlays As)
        __syncthreads();            // all MFMA reads of As/Ws complete
#pragma unroll
        for (int c = 0; c < 8; ++c) {
            unsigned u = __builtin_amdgcn_cvt_pk_fp8_f32(acc[c][0] * d, acc[c][1] * d, 0u, false);
            u = __builtin_amdgcn_cvt_pk_fp8_f32(acc[c][2] * d, acc[c][3] * d, u, true);
            *(unsigned*)(Cs + (m0 + cl) * 144 + c * 16 + kq * 4) = u;
        }
        __syncthreads();
        int row = t >> 2, off = (t & 3) * 32;
        if (rb + row < n) {
            uint4 q0 = *(const uint4*)(Cs + row * 144 + off);
            uint4 q1 = *(const uint4*)(Cs + row * 144 + off + 16);
            uchar* dst = C + (size_t)(rb + row) * HH + off;
            *(uint4*)dst = q0;
            *(uint4*)(dst + 16) = q1;
        }
    } else {
        // heads epilogue: lane (cl,kq) holds features {c*16+kq*4+r} of node m0+cl
        float s = 0.f;
#pragma unroll
        for (int c = 0; c < 8; ++c) {
            float4 bb = *(const float4*)(b1 + c * 16 + kq * 4);
            float4 ww = *(const float4*)(w2v + c * 16 + kq * 4);
            s += fmaxf(acc[c][0] + bb.x, 0.f) * ww.x;
            s += fmaxf(acc[c][1] + bb.y, 0.f) * ww.y;
            s += fmaxf(acc[c][2] + bb.z, 0.f) * ww.z;
            s += fmaxf(acc[c][3] + bb.w, 0.f) * ww.w;
        }
        s += __shfl_xor(s, 16, 64);
        s += __shfl_xor(s, 32, 64);
        unsigned mylmax = ENC_NEG_INF;
        if (kq == 0 && node < n) {
            float lg = s + b2[0];
            logits[node] = lg;
            if (rdy[m0 + cl] > 0) mylmax = encf(lg);
        }
        if (mylmax != ENC_NEG_INF) atomicMax(&slmax, mylmax);

        // mean / masked-max of h (bufB already relu'd): all 256 threads,
        // 2 row-halves of 32 + LDS combine
        int lim = min(64, n - rb);
        {
            int f = t & 127, h = t >> 7;
            int gf = f >> 3, fo = f & 7;
            float sum = 0.f, mx = -3.4e38f;
            int mlo = h * 32, mhi = min(lim, mlo + 32);
            for (int m = mlo; m < mhi; ++m) {
                float v = bf2f(As[m * HH + ((gf ^ (m & 15)) * 8) + fo]);
                sum += v;
                if (rdy[m] > 0) mx = fmaxf(mx, v);
            }
            if (h == 0) { xs[f] = sum; xmf[f] = mx; }
            __syncthreads();
            if (h == 1) {
                sum += xs[f];
                mx = fmaxf(mx, xmf[f]);
                int rep = blockIdx.x & (NREP - 1);
                atomicAdd(&meansum[rep * HH + f], sum);
                if (mx > -3.0e38f) atomicMax(&maxenc[rep * HH + f], encf(mx));
            }
        }
        __syncthreads();
        if (t == 0 && slmax != ENC_NEG_INF) atomicMax(lmaxenc, slmax);
    }
}

// ---------- small finalize: fc, pass-MLP, v, global max M ----------
__global__ void k_fin1(const float* __restrict__ meansum, const unsigned* __restrict__ maxenc,
                       const unsigned* __restrict__ lmaxenc,
                       const float* __restrict__ val_w, const float* __restrict__ val_b,
                       const float* __restrict__ pe, const float* __restrict__ cl_w,
                       const float* __restrict__ cl_b, const float* __restrict__ pw1,
                       const float* __restrict__ pb1, const float* __restrict__ pw2,
                       const float* __restrict__ pb2, float* __restrict__ scal,
                       float* __restrict__ d_out) {
    __shared__ float xp[144];
    __shared__ float msum[HH];
    __shared__ float zp[HH];
    int t = threadIdx.x;
    if (t < HH) {
        float s = 0.f;
        unsigned mx = ENC_NEG_INF;
        for (int r = 0; r < NREP; ++r) {
            s += meansum[r * HH + t];
            unsigned e = maxenc[r * HH + t];
            if (e > mx) mx = e;
        }
        msum[t] = s;
        xp[t] = decf(mx);
    } else if (t < 144) {
        int c = t - HH;
        float s = cl_b[c];
        for (int k = 0; k < 30; ++k) s += pe[k] * cl_w[k * 16 + c];
        xp[t] = s;
    }
    __syncthreads();
    if (t < HH) {
        float s = pb1[t];
        for (int k = 0; k < 144; ++k) s += xp[k] * pw1[k * HH + t];
        zp[t] = fmaxf(s, 0.f);
    }
    __syncthreads();
    if (t < 64) {
        float s1 = zp[t] * pw2[t] + zp[t + 64] * pw2[t + 64];
        float s2 = msum[t] * val_w[t] + msum[t + 64] * val_w[t + 64];
#pragma unroll
        for (int off = 32; off > 0; off >>= 1) {
            s1 += __shfl_xor(s1, off, 64);
            s2 += __shfl_xor(s2, off, 64);
        }
        if (t == 0) {
            float xpass = s1 + pb2[0];
            float v = s2 * (1.0f / NN) + val_b[0];
            float M = fmaxf(decf(lmaxenc[0]), xpass);
            scal[0] = M;
            scal[1] = expf(xpass - M);
            d_out[NN + 1] = v;
        }
    }
}

// ---------- exp pass: unnormalized probs + sum ----------
__global__ __launch_bounds__(256) void k_exp(const float* __restrict__ logits,
                                             const int* __restrict__ ready,
                                             const float* __restrict__ scal,
                                             float* __restrict__ d_out,
                                             float* __restrict__ esum) {
    __shared__ float warr[4];
    int t = threadIdx.x;
    int i = blockIdx.x * 256 + t;
    float M = scal[0];
    float p = 0.f;
    if (i < NN) {
        if (ready[i] > 0) p = expf(logits[i] - M);
        d_out[i] = p;
    }
    float s = p;
#pragma unroll
    for (int off = 32; off > 0; off >>= 1) s += __shfl_xor(s, off, 64);
    if ((t & 63) == 0) warr[t >> 6] = s;
    __syncthreads();
    if (t == 0) atomicAdd(esum, warr[0] + warr[1] + warr[2] + warr[3]);
}

// ---------- normalize ----------
__global__ void k_scale(const float* __restrict__ esum, const float* __restrict__ scal,
                        float* __restrict__ d_out) {
    int i = blockIdx.x * blockDim.x + threadIdx.x;
    float inv = 1.0f / (esum[0] + scal[1]);
    if (i < NN) d_out[i] *= inv;
    else if (i == NN) d_out[NN] = scal[1] * inv;
}

extern "C" void kernel_launch(void* const* d_in, const int* in_sizes, int n_in,
                              void* d_out, int out_size, void* d_ws, size_t ws_size,
                              hipStream_t stream) {
    const float* x      = (const float*)d_in[0];
    const int*   edges  = (const int*)d_in[1];
    const float* eattr  = (const float*)d_in[2];
    const int*   ready  = (const int*)d_in[3];
    const float* pe     = (const float*)d_in[4];
    const float* gcn_w  = (const float*)d_in[5];
    const float* gcn_b  = (const float*)d_in[6];
    const float* mlp_w1 = (const float*)d_in[7];
    const float* mlp_b1 = (const float*)d_in[8];
    const float* mlp_w2 = (const float*)d_in[9];
    const float* mlp_b2 = (const float*)d_in[10];
    const float* val_w  = (const float*)d_in[11];
    const float* val_b  = (const float*)d_in[12];
    const float* cl_w   = (const float*)d_in[13];
    const float* cl_b   = (const float*)d_in[14];
    const float* pw1    = (const float*)d_in[15];
    const float* pb1    = (const float*)d_in[16];
    const float* pw2    = (const float*)d_in[17];
    const float* pb2    = (const float*)d_in[18];

    const int* rows = edges;
    const int* cols = edges + EE;

    // workspace carving (256B-aligned slices)
    char* P = (char*)d_ws;
    size_t off = 0;
    auto carve = [&](size_t bytes) {
        off = (off + 255) & ~(size_t)255;
        void* p = P + off;
        off += bytes;
        return p;
    };
    float* dis     = (float*)carve(NN * 4);
    float* logits  = (float*)carve(NN * 4);
    int*   count   = (int*)carve(NN * 4);
    int*   basep   = (int*)carve(NN * 4);          // partial scan (pre block-offset)
    int*   base    = (int*)carve((NN + 1) * 4);    // final row starts (degsum-written)
    int*   bsum    = (int*)carve(256 * 4);
    ushort* bufB   = (ushort*)carve((size_t)NN * HH * 2);   // bf16 (gather out / gemm in)
    uchar* bufH    = (uchar*)carve((size_t)NN * HH);        // fp8 (gemm out / gather in)
    unsigned* csre = (unsigned*)carve((size_t)(EE + 8 * NN) * 4);  // padded CSR entries
    u64*   ebuck   = (u64*)carve((size_t)8 * CAP * 8);      // partition-major streams
    float* meansum = (float*)carve(NREP * HH * 4);
    unsigned* maxenc = (unsigned*)carve(NREP * HH * 4);
    unsigned* lmaxenc = (unsigned*)carve(4);
    float* esum    = (float*)carve(4);
    float* scal    = (float*)carve(8);
    int*   gtail   = (int*)carve(8 * 4);
    ushort* wt     = (ushort*)carve(3 * HH * HH * 2);

    // aliases (lifetime-disjoint with bufB, which k_gather first writes after fill2):
    unsigned* cntp   = (unsigned*)bufB;
    unsigned* deltap = (unsigned*)bufB + (size_t)8 * SS * HPP;

    float* out = (float*)d_out;

    const int nb = (NN + 255) / 256;
    const int gb = (NN + 63) / 64;          // mfma: 64-row blocks
    const int ab = (NN + 15) / 16;          // gather: 16-lane group per node
    const int pb = 8 * SS;                  // cnt2/fill2 blocks (256)

    k_setup<<<(3 * HH * HH + 255) / 256, 256, 0, stream>>>(meansum, maxenc, lmaxenc, esum,
                                                           gtail, gcn_w, gcn_w + HH * HH,
                                                           mlp_w1, wt);

    // CSR build: bucket -> cnt2 -> cntscan -> scan2 -> fill2 -> degsum
    k_bucket<<<NBB, 256, 0, stream>>>(rows, cols, eattr, gtail, ebuck);
    k_cnt2<<<pb, 256, 0, stream>>>(ebuck, gtail, cntp);
    k_cntscan<<<NSCAN, 256, 0, stream>>>(cntp, count, deltap, basep, bsum);
    k_scan2<<<1, 256, 0, stream>>>(bsum, base);
    k_fill2<<<pb, 256, 0, stream>>>(ebuck, gtail, deltap, basep, bsum, csre);
    k_degsum<<<nb, 256, 0, stream>>>(count, csre, basep, bsum, base, dis);

    // layer 0
    k_mfma<0><<<gb, 256, 0, stream>>>(x, wt, bufH, dis, nullptr, nullptr, nullptr, nullptr,
                                      nullptr, nullptr, nullptr, nullptr, NN);
    k_gather<<<ab, 256, 0, stream>>>(bufH, csre, base, dis, gcn_b, bufB);

    // layer 1
    k_mfma<1><<<gb, 256, 0, stream>>>(bufB, wt + HH * HH, bufH, dis, nullptr, nullptr, nullptr,
                                      nullptr, nullptr, nullptr, nullptr, nullptr, NN);
    k_gather<<<ab, 256, 0, stream>>>(bufH, csre, base, dis, gcn_b + HH, bufB);

    // heads
    k_mfma<2><<<gb, 256, 0, stream>>>(bufB, wt + 2 * HH * HH, nullptr, nullptr, mlp_b1, mlp_w2,
                                      mlp_b2, ready, logits, meansum, maxenc, lmaxenc, NN);
    k_fin1<<<1, 256, 0, stream>>>(meansum, maxenc, lmaxenc, val_w, val_b, pe, cl_w, cl_b,
                                  pw1, pb1, pw2, pb2, scal, out);
    k_exp<<<nb, 256, 0, stream>>>(logits, ready, scal, out, esum);
    k_scale<<<(NN + 1 + 255) / 256, 256, 0, stream>>>(esum, scal, out);
}